// Round 1
// baseline (913.174 us; speedup 1.0000x reference)
//
#include <hip/hip_runtime.h>
#include <math.h>

#define NGRAPH 128
#define KTOP 30
#define LATENT 193
#define HID 64

// ---------------- init ----------------
__global__ void k_init(int* deg, int* counts, int n) {
    int i = blockIdx.x * blockDim.x + threadIdx.x;
    if (i < n) deg[i] = 1;            // self-loop
    if (i < NGRAPH) counts[i] = 0;
}

// deg histogram over edge dst + batch histogram
__global__ void k_hist(const int* __restrict__ dst, const int* __restrict__ batch,
                       int* deg, int* counts, int E, int n) {
    int i = blockIdx.x * blockDim.x + threadIdx.x;
    if (i < E) {
        atomicAdd(&deg[dst[i]], 1);
    } else {
        int j = i - E;
        if (j < n) atomicAdd(&counts[batch[j]], 1);
    }
}

__global__ void k_dinv(const int* __restrict__ deg, float* dinv, int n) {
    int i = blockIdx.x * blockDim.x + threadIdx.x;
    if (i < n) dinv[i] = rsqrtf((float)deg[i]);
}

// exclusive scan of 128 counts (1 block, 128 threads)
__global__ void k_scan(const int* __restrict__ counts, int* starts) {
    __shared__ int s[NGRAPH];
    int t = threadIdx.x;
    s[t] = counts[t];
    __syncthreads();
    for (int o = 1; o < NGRAPH; o <<= 1) {
        int add = (t >= o) ? s[t - o] : 0;
        __syncthreads();
        s[t] += add;
        __syncthreads();
    }
    starts[t] = s[t] - counts[t];
}

// ---------------- GEMM: Hs = (A @ W) * dinv[row]; Acc = Hs ----------------
// A: MxK row-major, W: Kx64 row-major. BM=64, BN=64, BK=16, 256 threads, 4x4/thread.
__global__ __launch_bounds__(256) void k_gemm(const float* __restrict__ A,
                                              const float* __restrict__ W,
                                              const float* __restrict__ dinv,
                                              float* __restrict__ Hs,
                                              float* __restrict__ Acc,
                                              int M, int K) {
    __shared__ float As[64][17];
    __shared__ float Bs[16][65];
    int tid = threadIdx.x;
    int tx = tid & 15, ty = tid >> 4;
    int br = blockIdx.x * 64;
    float c[4][4] = {};
    for (int k0 = 0; k0 < K; k0 += 16) {
        {   // A tile 64x16, 4 consecutive floats per thread
            int idx = tid * 4;
            int r = idx >> 4;
            int kk = idx & 15;
            int grow = br + r;
            float4 v = make_float4(0.f, 0.f, 0.f, 0.f);
            if (grow < M) v = *(const float4*)(A + (size_t)grow * K + k0 + kk);
            As[r][kk + 0] = v.x; As[r][kk + 1] = v.y;
            As[r][kk + 2] = v.z; As[r][kk + 3] = v.w;
        }
        {   // B tile 16x64
            int idx = tid * 4;
            int kk = idx >> 6;
            int col = idx & 63;
            float4 v = *(const float4*)(W + (size_t)(k0 + kk) * 64 + col);
            Bs[kk][col + 0] = v.x; Bs[kk][col + 1] = v.y;
            Bs[kk][col + 2] = v.z; Bs[kk][col + 3] = v.w;
        }
        __syncthreads();
#pragma unroll
        for (int kk = 0; kk < 16; ++kk) {
            float a[4], b[4];
#pragma unroll
            for (int i = 0; i < 4; i++) a[i] = As[ty + i * 16][kk];
#pragma unroll
            for (int j = 0; j < 4; j++) b[j] = Bs[kk][tx + j * 16];
#pragma unroll
            for (int i = 0; i < 4; i++)
#pragma unroll
                for (int j = 0; j < 4; j++) c[i][j] += a[i] * b[j];
        }
        __syncthreads();
    }
#pragma unroll
    for (int i = 0; i < 4; i++) {
        int row = br + ty + i * 16;
        if (row >= M) continue;
        float d = dinv[row];
#pragma unroll
        for (int j = 0; j < 4; j++) {
            int col = tx + j * 16;
            float v = c[i][j] * d;
            Hs[(size_t)row * HID + col] = v;
            Acc[(size_t)row * HID + col] = v;
        }
    }
}

// ---------------- edge scatter: Acc[dst] += Hs[src] (64 feats) ----------------
__global__ __launch_bounds__(256) void k_scatter(const int* __restrict__ src,
                                                 const int* __restrict__ dst,
                                                 const float* __restrict__ Hs,
                                                 float* __restrict__ Acc, int E) {
    int t = blockIdx.x * 256 + threadIdx.x;
    int e = t >> 6;
    int f = t & 63;
    if (e < E) {
        int s = src[e], d = dst[e];
        atomicAdd(&Acc[(size_t)d * HID + f], Hs[(size_t)s * HID + f]);
    }
}

// ---------------- epilogue: H = tanh(Acc * dinv[row] + b[col]) ----------------
__global__ void k_finish(const float* __restrict__ Acc, const float* __restrict__ dinv,
                         const float* __restrict__ b, float* __restrict__ H, int n) {
    int t = blockIdx.x * blockDim.x + threadIdx.x;
    if (t < n * HID) {
        int i = t >> 6, f = t & 63;
        H[t] = tanhf(Acc[t] * dinv[i] + b[f]);
    }
}

// ---------------- layer 4: ts = (h3 . w3) * dinv ; acc4 = ts ----------------
__global__ __launch_bounds__(256) void k_gemv4(const float* __restrict__ h3,
                                               const float* __restrict__ w3,
                                               const float* __restrict__ dinv,
                                               float* ts, float* acc4, int n) {
    int wid = threadIdx.x >> 6;
    int lane = threadIdx.x & 63;
    int node = blockIdx.x * 4 + wid;
    if (node >= n) return;
    float v = h3[(size_t)node * HID + lane] * w3[lane];
    for (int o = 32; o > 0; o >>= 1) v += __shfl_down(v, o, 64);
    if (lane == 0) {
        float tv = v * dinv[node];
        ts[node] = tv;
        acc4[node] = tv;
    }
}

__global__ void k_scatter4(const int* __restrict__ src, const int* __restrict__ dst,
                           const float* __restrict__ ts, float* acc4, int E) {
    int e = blockIdx.x * blockDim.x + threadIdx.x;
    if (e < E) atomicAdd(&acc4[dst[e]], ts[src[e]]);
}

__global__ void k_finish4(const float* __restrict__ acc4, const float* __restrict__ dinv,
                          const float* __restrict__ b3, float* h4, int n) {
    int i = blockIdx.x * blockDim.x + threadIdx.x;
    if (i < n) h4[i] = tanhf(acc4[i] * dinv[i] + b3[0]);
}

// ---------------- top-K selection per graph ----------------
// descending by h4, tie -> smaller node index (stable lexsort semantics)
__global__ __launch_bounds__(256) void k_select(const float* __restrict__ h4,
                                                const int* __restrict__ starts,
                                                const int* __restrict__ counts,
                                                int* sel) {
    int g = blockIdx.x;
    int s = starts[g], c = counts[g];
    __shared__ float bv[256];
    __shared__ int bi[256];
    __shared__ float pvs;
    __shared__ int pis;
    float pv = 1e30f;
    int pi = -1;
    for (int slot = 0; slot < KTOP; ++slot) {
        float best = -1e30f;
        int bestI = 0x7fffffff;
        for (int i = threadIdx.x; i < c; i += 256) {
            int node = s + i;
            float v = h4[node];
            bool after = (v < pv) || (v == pv && node > pi);
            if (after) {
                if (v > best || (v == best && node < bestI)) { best = v; bestI = node; }
            }
        }
        bv[threadIdx.x] = best;
        bi[threadIdx.x] = bestI;
        __syncthreads();
        for (int o = 128; o > 0; o >>= 1) {
            if (threadIdx.x < o) {
                float v2 = bv[threadIdx.x + o];
                int i2 = bi[threadIdx.x + o];
                if (v2 > bv[threadIdx.x] ||
                    (v2 == bv[threadIdx.x] && i2 < bi[threadIdx.x])) {
                    bv[threadIdx.x] = v2;
                    bi[threadIdx.x] = i2;
                }
            }
            __syncthreads();
        }
        if (threadIdx.x == 0) {
            sel[g * KTOP + slot] = (slot < c) ? bi[0] : -1;
            pvs = bv[0];
            pis = bi[0];
        }
        __syncthreads();
        pv = pvs;
        pi = pis;
        __syncthreads();
    }
}

// ---------------- tail: gather latent -> conv1 -> maxpool -> conv2 -> MLP ----------------
__global__ __launch_bounds__(256) void k_tail(const float* __restrict__ h1,
                                              const float* __restrict__ h2,
                                              const float* __restrict__ h3,
                                              const float* __restrict__ h4,
                                              const int* __restrict__ sel,
                                              const float* __restrict__ c1w,
                                              const float* __restrict__ c1b,
                                              const float* __restrict__ c2w,
                                              const float* __restrict__ c2b,
                                              const float* __restrict__ l1w,
                                              const float* __restrict__ l1b,
                                              const float* __restrict__ l2w,
                                              const float* __restrict__ l2b,
                                              float* __restrict__ out) {
    __shared__ float p[KTOP * LATENT];    // 5790
    __shared__ float w1s[16 * LATENT];    // 3088
    __shared__ float z1[16 * KTOP];       // 480
    __shared__ float z1p[16 * 15];        // 240
    __shared__ float w2s[32 * 16 * 5];    // 2560
    __shared__ float flat[352];
    __shared__ float y1[256];
    int g = blockIdx.x;
    int t = threadIdx.x;
    for (int i = t; i < 16 * LATENT; i += 256) w1s[i] = c1w[i];
    for (int i = t; i < 32 * 16 * 5; i += 256) w2s[i] = c2w[i];
    for (int i = t; i < KTOP * LATENT; i += 256) {
        int slot = i / LATENT;
        int j = i - slot * LATENT;
        int node = sel[g * KTOP + slot];
        float v = 0.f;
        if (node >= 0) {
            if (j < 64)       v = h1[(size_t)node * HID + j];
            else if (j < 128) v = h2[(size_t)node * HID + j - 64];
            else if (j < 192) v = h3[(size_t)node * HID + j - 128];
            else              v = h4[node];
        }
        p[i] = v;
    }
    __syncthreads();
    // conv1 (per-slot linear 193->16) + relu
    for (int o = t; o < 16 * KTOP; o += 256) {
        int ch = o / KTOP, tt = o - ch * KTOP;
        float s = c1b[ch];
        const float* wp = &w1s[ch * LATENT];
        const float* pp = &p[tt * LATENT];
        for (int j = 0; j < LATENT; j++) s += pp[j] * wp[j];
        z1[ch * KTOP + tt] = fmaxf(s, 0.f);
    }
    __syncthreads();
    // maxpool pairs 30->15
    for (int o = t; o < 16 * 15; o += 256) {
        int ch = o / 15, tt = o - ch * 15;
        z1p[o] = fmaxf(z1[ch * KTOP + 2 * tt], z1[ch * KTOP + 2 * tt + 1]);
    }
    __syncthreads();
    // conv2 (16ch x 5 tap -> 32ch, len 15->11) + relu, flatten c2*11+t
    for (int o = t; o < 32 * 11; o += 256) {
        int c2 = o / 11, tt = o - c2 * 11;
        float s = c2b[c2];
        for (int c1i = 0; c1i < 16; c1i++) {
            const float* wp = &w2s[(c2 * 16 + c1i) * 5];
            const float* zp = &z1p[c1i * 15 + tt];
#pragma unroll
            for (int dt = 0; dt < 5; dt++) s += zp[dt] * wp[dt];
        }
        flat[c2 * 11 + tt] = fmaxf(s, 0.f);
    }
    __syncthreads();
    // lin1 352->256 + relu
    {
        float s = l1b[t];
        for (int i = 0; i < 352; i++) s += flat[i] * l1w[i * 256 + t];
        y1[t] = fmaxf(s, 0.f);
    }
    __syncthreads();
    // lin2 256->2
    if (t < 2) {
        float s = l2b[t];
        for (int i = 0; i < 256; i++) s += y1[i] * l2w[i * 2 + t];
        out[g * 2 + t] = s;
    }
}

// ---------------- launch ----------------
static inline char* align256(char* p) {
    return (char*)(((uintptr_t)p + 255) & ~(uintptr_t)255);
}

extern "C" void kernel_launch(void* const* d_in, const int* in_sizes, int n_in,
                              void* d_out, int out_size, void* d_ws, size_t ws_size,
                              hipStream_t stream) {
    const float* x     = (const float*)d_in[0];
    const int*  eidx   = (const int*)d_in[1];
    const int*  batch  = (const int*)d_in[2];
    const float* w0    = (const float*)d_in[3];
    const float* b0    = (const float*)d_in[4];
    const float* w1    = (const float*)d_in[5];
    const float* b1    = (const float*)d_in[6];
    const float* w2    = (const float*)d_in[7];
    const float* b2    = (const float*)d_in[8];
    const float* w3    = (const float*)d_in[9];
    const float* b3    = (const float*)d_in[10];
    const float* c1w   = (const float*)d_in[11];
    const float* c1b   = (const float*)d_in[12];
    const float* c2w   = (const float*)d_in[13];
    const float* c2b   = (const float*)d_in[14];
    const float* l1w   = (const float*)d_in[15];
    const float* l1b   = (const float*)d_in[16];
    const float* l2w   = (const float*)d_in[17];
    const float* l2b   = (const float*)d_in[18];

    int N = in_sizes[2];              // 50000 nodes
    int E = in_sizes[1] / 2;          // 800000 edges
    int K0 = in_sizes[0] / N;         // 128 input feats
    const int* esrc = eidx;
    const int* edst = eidx + E;

    char* w = (char*)d_ws;
    float* dinv = (float*)w;              w = align256(w + (size_t)N * 4);
    int*   deg  = (int*)w;                w = align256(w + (size_t)N * 4);
    float* ts   = (float*)w;              w = align256(w + (size_t)N * 4);
    float* acc4 = (float*)w;              w = align256(w + (size_t)N * 4);
    float* h4   = (float*)w;              w = align256(w + (size_t)N * 4);
    int* counts = (int*)w;                w = align256(w + NGRAPH * 4);
    int* starts = (int*)w;                w = align256(w + NGRAPH * 4);
    int* sel    = (int*)w;                w = align256(w + NGRAPH * KTOP * 4);
    float* Hs   = (float*)w;              w = align256(w + (size_t)N * HID * 4);
    float* Acc  = (float*)w;              w = align256(w + (size_t)N * HID * 4);
    float* h1   = (float*)w;              w = align256(w + (size_t)N * HID * 4);
    float* h2   = (float*)w;              w = align256(w + (size_t)N * HID * 4);
    float* h3   = (float*)w;              w = align256(w + (size_t)N * HID * 4);

    // degree + batch histogram
    k_init<<<(N + 255) / 256, 256, 0, stream>>>(deg, counts, N);
    {
        int total = E + N;
        k_hist<<<(total + 255) / 256, 256, 0, stream>>>(edst, batch, deg, counts, E, N);
    }
    k_dinv<<<(N + 255) / 256, 256, 0, stream>>>(deg, dinv, N);
    k_scan<<<1, NGRAPH, 0, stream>>>(counts, starts);

    int gemm_grid = (N + 63) / 64;
    int scat_grid = (int)(((size_t)E * 64 + 255) / 256);
    int fin_grid  = (int)(((size_t)N * 64 + 255) / 256);

    // layer 1: x (K=128) -> h1
    k_gemm<<<gemm_grid, 256, 0, stream>>>(x, w0, dinv, Hs, Acc, N, K0);
    k_scatter<<<scat_grid, 256, 0, stream>>>(esrc, edst, Hs, Acc, E);
    k_finish<<<fin_grid, 256, 0, stream>>>(Acc, dinv, b0, h1, N);
    // layer 2
    k_gemm<<<gemm_grid, 256, 0, stream>>>(h1, w1, dinv, Hs, Acc, N, HID);
    k_scatter<<<scat_grid, 256, 0, stream>>>(esrc, edst, Hs, Acc, E);
    k_finish<<<fin_grid, 256, 0, stream>>>(Acc, dinv, b1, h2, N);
    // layer 3
    k_gemm<<<gemm_grid, 256, 0, stream>>>(h2, w2, dinv, Hs, Acc, N, HID);
    k_scatter<<<scat_grid, 256, 0, stream>>>(esrc, edst, Hs, Acc, E);
    k_finish<<<fin_grid, 256, 0, stream>>>(Acc, dinv, b2, h3, N);
    // layer 4 (64 -> 1)
    k_gemv4<<<(N + 3) / 4, 256, 0, stream>>>(h3, w3, dinv, ts, acc4, N);
    k_scatter4<<<(E + 255) / 256, 256, 0, stream>>>(esrc, edst, ts, acc4, E);
    k_finish4<<<(N + 255) / 256, 256, 0, stream>>>(acc4, dinv, b3, h4, N);

    // sort-pool top-30 per graph
    k_select<<<NGRAPH, 256, 0, stream>>>(h4, starts, counts, sel);

    // tail
    k_tail<<<NGRAPH, 256, 0, stream>>>(h1, h2, h3, h4, sel,
                                       c1w, c1b, c2w, c2b,
                                       l1w, l1b, l2w, l2b,
                                       (float*)d_out);
}

// Round 2
// 495.001 us; speedup vs baseline: 1.8448x; 1.8448x over previous
//
#include <hip/hip_runtime.h>
#include <math.h>

#define NGRAPH 128
#define KTOP 30
#define LATENT 193
#define HID 64

// ---------------- init: edeg=0, counts=0, cursor=0 ----------------
__global__ void k_init(int* edeg, int* counts, int* cursor, int n) {
    int i = blockIdx.x * blockDim.x + threadIdx.x;
    if (i < n) { edeg[i] = 0; cursor[i] = 0; }
    if (i < NGRAPH) counts[i] = 0;
}

// in-degree histogram over edge dst + batch histogram
__global__ void k_hist(const int* __restrict__ dst, const int* __restrict__ batch,
                       int* edeg, int* counts, int E, int n) {
    int i = blockIdx.x * blockDim.x + threadIdx.x;
    if (i < E) {
        atomicAdd(&edeg[dst[i]], 1);
    } else {
        int j = i - E;
        if (j < n) atomicAdd(&counts[batch[j]], 1);
    }
}

__global__ void k_dinv(const int* __restrict__ edeg, float* dinv, int n) {
    int i = blockIdx.x * blockDim.x + threadIdx.x;
    if (i < n) dinv[i] = rsqrtf((float)(edeg[i] + 1));   // +1 self-loop
}

// ---------------- hierarchical exclusive scan of edeg -> offs ----------------
__global__ void k_scan1(const int* __restrict__ edeg, int* offs, int* bsum, int n) {
    __shared__ int s[256];
    int t = threadIdx.x;
    int gi = blockIdx.x * 256 + t;
    int v = (gi < n) ? edeg[gi] : 0;
    s[t] = v;
    __syncthreads();
    for (int o = 1; o < 256; o <<= 1) {
        int add = (t >= o) ? s[t - o] : 0;
        __syncthreads();
        s[t] += add;
        __syncthreads();
    }
    if (gi < n) offs[gi] = s[t] - v;          // local exclusive
    if (t == 255) bsum[blockIdx.x] = s[255];
}

__global__ void k_scan2(int* bsum, int* boff, int nb) {
    __shared__ int s[256];
    int t = threadIdx.x;
    int v = (t < nb) ? bsum[t] : 0;
    s[t] = v;
    __syncthreads();
    for (int o = 1; o < 256; o <<= 1) {
        int add = (t >= o) ? s[t - o] : 0;
        __syncthreads();
        s[t] += add;
        __syncthreads();
    }
    if (t < nb) boff[t] = s[t] - v;
}

__global__ void k_scan3(int* offs, const int* __restrict__ boff, int n, int E) {
    int gi = blockIdx.x * blockDim.x + threadIdx.x;
    if (gi < n) offs[gi] += boff[gi >> 8];
    if (gi == 0) offs[n] = E;
}

// ---------------- fill CSR: csr[offs[dst]+cursor[dst]++] = src ----------------
__global__ void k_fill(const int* __restrict__ src, const int* __restrict__ dst,
                       const int* __restrict__ offs, int* cursor,
                       int* __restrict__ csr, int E) {
    int e = blockIdx.x * blockDim.x + threadIdx.x;
    if (e < E) {
        int d = dst[e];
        int pos = offs[d] + atomicAdd(&cursor[d], 1);
        csr[pos] = src[e];
    }
}

// ---------------- GEMM: Hs = (A @ W) * dinv[row] ----------------
// A: MxK row-major, W: Kx64 row-major. BM=64, BN=64, BK=16, 256 threads, 4x4/thread.
__global__ __launch_bounds__(256) void k_gemm(const float* __restrict__ A,
                                              const float* __restrict__ W,
                                              const float* __restrict__ dinv,
                                              float* __restrict__ Hs,
                                              int M, int K) {
    __shared__ float As[64][17];
    __shared__ float Bs[16][65];
    int tid = threadIdx.x;
    int tx = tid & 15, ty = tid >> 4;
    int br = blockIdx.x * 64;
    float c[4][4] = {};
    for (int k0 = 0; k0 < K; k0 += 16) {
        {   // A tile 64x16
            int idx = tid * 4;
            int r = idx >> 4;
            int kk = idx & 15;
            int grow = br + r;
            float4 v = make_float4(0.f, 0.f, 0.f, 0.f);
            if (grow < M) v = *(const float4*)(A + (size_t)grow * K + k0 + kk);
            As[r][kk + 0] = v.x; As[r][kk + 1] = v.y;
            As[r][kk + 2] = v.z; As[r][kk + 3] = v.w;
        }
        {   // B tile 16x64
            int idx = tid * 4;
            int kk = idx >> 6;
            int col = idx & 63;
            float4 v = *(const float4*)(W + (size_t)(k0 + kk) * 64 + col);
            Bs[kk][col + 0] = v.x; Bs[kk][col + 1] = v.y;
            Bs[kk][col + 2] = v.z; Bs[kk][col + 3] = v.w;
        }
        __syncthreads();
#pragma unroll
        for (int kk = 0; kk < 16; ++kk) {
            float a[4], b[4];
#pragma unroll
            for (int i = 0; i < 4; i++) a[i] = As[ty + i * 16][kk];
#pragma unroll
            for (int j = 0; j < 4; j++) b[j] = Bs[kk][tx + j * 16];
#pragma unroll
            for (int i = 0; i < 4; i++)
#pragma unroll
                for (int j = 0; j < 4; j++) c[i][j] += a[i] * b[j];
        }
        __syncthreads();
    }
#pragma unroll
    for (int i = 0; i < 4; i++) {
        int row = br + ty + i * 16;
        if (row >= M) continue;
        float d = dinv[row];
#pragma unroll
        for (int j = 0; j < 4; j++) {
            int col = tx + j * 16;
            Hs[(size_t)row * HID + col] = c[i][j] * d;
        }
    }
}

// ------- aggregate (gather, wave per node) + fused tanh epilogue -------
// H[n][f] = tanh( (Hs[n][f] + sum_{u in CSR[n]} Hs[u][f]) * dinv[n] + b[f] )
__global__ __launch_bounds__(256) void k_agg(const float* __restrict__ Hs,
                                             const int* __restrict__ csr,
                                             const int* __restrict__ offs,
                                             const float* __restrict__ dinv,
                                             const float* __restrict__ b,
                                             float* __restrict__ H, int n) {
    int wid = threadIdx.x >> 6;
    int lane = threadIdx.x & 63;
    int node = blockIdx.x * 4 + wid;
    if (node >= n) return;
    float acc = Hs[(size_t)node * HID + lane];     // self-loop term
    int s = offs[node], e = offs[node + 1];
    int i = s;
    for (; i + 4 <= e; i += 4) {
        int u0 = csr[i], u1 = csr[i + 1], u2 = csr[i + 2], u3 = csr[i + 3];
        float v0 = Hs[(size_t)u0 * HID + lane];
        float v1 = Hs[(size_t)u1 * HID + lane];
        float v2 = Hs[(size_t)u2 * HID + lane];
        float v3 = Hs[(size_t)u3 * HID + lane];
        acc += v0 + v1 + v2 + v3;
    }
    for (; i < e; i++) acc += Hs[(size_t)csr[i] * HID + lane];
    H[(size_t)node * HID + lane] = tanhf(acc * dinv[node] + b[lane]);
}

// ---------------- layer 4: ts = (h3 . w3) * dinv ----------------
__global__ __launch_bounds__(256) void k_gemv4(const float* __restrict__ h3,
                                               const float* __restrict__ w3,
                                               const float* __restrict__ dinv,
                                               float* ts, int n) {
    int wid = threadIdx.x >> 6;
    int lane = threadIdx.x & 63;
    int node = blockIdx.x * 4 + wid;
    if (node >= n) return;
    float v = h3[(size_t)node * HID + lane] * w3[lane];
    for (int o = 32; o > 0; o >>= 1) v += __shfl_down(v, o, 64);
    if (lane == 0) ts[node] = v * dinv[node];
}

// layer-4 aggregate + finish: h4 = tanh((ts[n] + sum ts[u]) * dinv[n] + b3)
__global__ void k_agg4(const float* __restrict__ ts, const int* __restrict__ csr,
                       const int* __restrict__ offs, const float* __restrict__ dinv,
                       const float* __restrict__ b3, float* h4, int n) {
    int node = blockIdx.x * blockDim.x + threadIdx.x;
    if (node >= n) return;
    float acc = ts[node];
    int s = offs[node], e = offs[node + 1];
    for (int i = s; i < e; i++) acc += ts[csr[i]];
    h4[node] = tanhf(acc * dinv[node] + b3[0]);
}

// exclusive scan of 128 counts (1 block, 128 threads)
__global__ void k_scan_g(const int* __restrict__ counts, int* starts) {
    __shared__ int s[NGRAPH];
    int t = threadIdx.x;
    s[t] = counts[t];
    __syncthreads();
    for (int o = 1; o < NGRAPH; o <<= 1) {
        int add = (t >= o) ? s[t - o] : 0;
        __syncthreads();
        s[t] += add;
        __syncthreads();
    }
    starts[t] = s[t] - counts[t];
}

// ---------------- top-K selection per graph ----------------
__global__ __launch_bounds__(256) void k_select(const float* __restrict__ h4,
                                                const int* __restrict__ starts,
                                                const int* __restrict__ counts,
                                                int* sel) {
    int g = blockIdx.x;
    int s = starts[g], c = counts[g];
    __shared__ float bv[256];
    __shared__ int bi[256];
    __shared__ float pvs;
    __shared__ int pis;
    float pv = 1e30f;
    int pi = -1;
    for (int slot = 0; slot < KTOP; ++slot) {
        float best = -1e30f;
        int bestI = 0x7fffffff;
        for (int i = threadIdx.x; i < c; i += 256) {
            int node = s + i;
            float v = h4[node];
            bool after = (v < pv) || (v == pv && node > pi);
            if (after) {
                if (v > best || (v == best && node < bestI)) { best = v; bestI = node; }
            }
        }
        bv[threadIdx.x] = best;
        bi[threadIdx.x] = bestI;
        __syncthreads();
        for (int o = 128; o > 0; o >>= 1) {
            if (threadIdx.x < o) {
                float v2 = bv[threadIdx.x + o];
                int i2 = bi[threadIdx.x + o];
                if (v2 > bv[threadIdx.x] ||
                    (v2 == bv[threadIdx.x] && i2 < bi[threadIdx.x])) {
                    bv[threadIdx.x] = v2;
                    bi[threadIdx.x] = i2;
                }
            }
            __syncthreads();
        }
        if (threadIdx.x == 0) {
            sel[g * KTOP + slot] = (slot < c) ? bi[0] : -1;
            pvs = bv[0];
            pis = bi[0];
        }
        __syncthreads();
        pv = pvs;
        pi = pis;
        __syncthreads();
    }
}

// ---------------- tail ----------------
__global__ __launch_bounds__(256) void k_tail(const float* __restrict__ h1,
                                              const float* __restrict__ h2,
                                              const float* __restrict__ h3,
                                              const float* __restrict__ h4,
                                              const int* __restrict__ sel,
                                              const float* __restrict__ c1w,
                                              const float* __restrict__ c1b,
                                              const float* __restrict__ c2w,
                                              const float* __restrict__ c2b,
                                              const float* __restrict__ l1w,
                                              const float* __restrict__ l1b,
                                              const float* __restrict__ l2w,
                                              const float* __restrict__ l2b,
                                              float* __restrict__ out) {
    __shared__ float p[KTOP * LATENT];
    __shared__ float w1s[16 * LATENT];
    __shared__ float z1[16 * KTOP];
    __shared__ float z1p[16 * 15];
    __shared__ float w2s[32 * 16 * 5];
    __shared__ float flat[352];
    __shared__ float y1[256];
    int g = blockIdx.x;
    int t = threadIdx.x;
    for (int i = t; i < 16 * LATENT; i += 256) w1s[i] = c1w[i];
    for (int i = t; i < 32 * 16 * 5; i += 256) w2s[i] = c2w[i];
    for (int i = t; i < KTOP * LATENT; i += 256) {
        int slot = i / LATENT;
        int j = i - slot * LATENT;
        int node = sel[g * KTOP + slot];
        float v = 0.f;
        if (node >= 0) {
            if (j < 64)       v = h1[(size_t)node * HID + j];
            else if (j < 128) v = h2[(size_t)node * HID + j - 64];
            else if (j < 192) v = h3[(size_t)node * HID + j - 128];
            else              v = h4[node];
        }
        p[i] = v;
    }
    __syncthreads();
    for (int o = t; o < 16 * KTOP; o += 256) {
        int ch = o / KTOP, tt = o - ch * KTOP;
        float s = c1b[ch];
        const float* wp = &w1s[ch * LATENT];
        const float* pp = &p[tt * LATENT];
        for (int j = 0; j < LATENT; j++) s += pp[j] * wp[j];
        z1[ch * KTOP + tt] = fmaxf(s, 0.f);
    }
    __syncthreads();
    for (int o = t; o < 16 * 15; o += 256) {
        int ch = o / 15, tt = o - ch * 15;
        z1p[o] = fmaxf(z1[ch * KTOP + 2 * tt], z1[ch * KTOP + 2 * tt + 1]);
    }
    __syncthreads();
    for (int o = t; o < 32 * 11; o += 256) {
        int c2 = o / 11, tt = o - c2 * 11;
        float s = c2b[c2];
        for (int c1i = 0; c1i < 16; c1i++) {
            const float* wp = &w2s[(c2 * 16 + c1i) * 5];
            const float* zp = &z1p[c1i * 15 + tt];
#pragma unroll
            for (int dt = 0; dt < 5; dt++) s += zp[dt] * wp[dt];
        }
        flat[c2 * 11 + tt] = fmaxf(s, 0.f);
    }
    __syncthreads();
    {
        float s = l1b[t];
        for (int i = 0; i < 352; i++) s += flat[i] * l1w[i * 256 + t];
        y1[t] = fmaxf(s, 0.f);
    }
    __syncthreads();
    if (t < 2) {
        float s = l2b[t];
        for (int i = 0; i < 256; i++) s += y1[i] * l2w[i * 2 + t];
        out[g * 2 + t] = s;
    }
}

// ---------------- launch ----------------
static inline char* align256(char* p) {
    return (char*)(((uintptr_t)p + 255) & ~(uintptr_t)255);
}

extern "C" void kernel_launch(void* const* d_in, const int* in_sizes, int n_in,
                              void* d_out, int out_size, void* d_ws, size_t ws_size,
                              hipStream_t stream) {
    const float* x     = (const float*)d_in[0];
    const int*  eidx   = (const int*)d_in[1];
    const int*  batch  = (const int*)d_in[2];
    const float* w0    = (const float*)d_in[3];
    const float* b0    = (const float*)d_in[4];
    const float* w1    = (const float*)d_in[5];
    const float* b1    = (const float*)d_in[6];
    const float* w2    = (const float*)d_in[7];
    const float* b2    = (const float*)d_in[8];
    const float* w3    = (const float*)d_in[9];
    const float* b3    = (const float*)d_in[10];
    const float* c1w   = (const float*)d_in[11];
    const float* c1b   = (const float*)d_in[12];
    const float* c2w   = (const float*)d_in[13];
    const float* c2b   = (const float*)d_in[14];
    const float* l1w   = (const float*)d_in[15];
    const float* l1b   = (const float*)d_in[16];
    const float* l2w   = (const float*)d_in[17];
    const float* l2b   = (const float*)d_in[18];

    int N = in_sizes[2];              // 50000 nodes
    int E = in_sizes[1] / 2;          // 800000 edges
    int K0 = in_sizes[0] / N;         // 128 input feats
    const int* esrc = eidx;
    const int* edst = eidx + E;

    char* w = (char*)d_ws;
    float* dinv  = (float*)w;             w = align256(w + (size_t)N * 4);
    int*   edeg  = (int*)w;               w = align256(w + (size_t)N * 4);
    int*   cursor= (int*)w;               w = align256(w + (size_t)N * 4);
    int*   offs  = (int*)w;               w = align256(w + (size_t)(N + 1) * 4);
    int*   bsum  = (int*)w;               w = align256(w + 1024);
    int*   boff  = (int*)w;               w = align256(w + 1024);
    float* ts    = (float*)w;             w = align256(w + (size_t)N * 4);
    float* h4    = (float*)w;             w = align256(w + (size_t)N * 4);
    int* counts  = (int*)w;               w = align256(w + NGRAPH * 4);
    int* starts  = (int*)w;               w = align256(w + NGRAPH * 4);
    int* sel     = (int*)w;               w = align256(w + NGRAPH * KTOP * 4);
    int* csr     = (int*)w;               w = align256(w + (size_t)E * 4);
    float* Hs    = (float*)w;             w = align256(w + (size_t)N * HID * 4);
    float* h1    = (float*)w;             w = align256(w + (size_t)N * HID * 4);
    float* h2    = (float*)w;             w = align256(w + (size_t)N * HID * 4);
    float* h3    = (float*)w;             w = align256(w + (size_t)N * HID * 4);

    int nb = (N + 255) / 256;

    // histograms + dinv
    k_init<<<(N + 255) / 256, 256, 0, stream>>>(edeg, counts, cursor, N);
    k_hist<<<(E + N + 255) / 256, 256, 0, stream>>>(edst, batch, edeg, counts, E, N);
    k_dinv<<<(N + 255) / 256, 256, 0, stream>>>(edeg, dinv, N);

    // CSR build
    k_scan1<<<nb, 256, 0, stream>>>(edeg, offs, bsum, N);
    k_scan2<<<1, 256, 0, stream>>>(bsum, boff, nb);
    k_scan3<<<nb, 256, 0, stream>>>(offs, boff, N, E);
    k_fill<<<(E + 255) / 256, 256, 0, stream>>>(esrc, edst, offs, cursor, csr, E);

    // graph-start scan
    k_scan_g<<<1, NGRAPH, 0, stream>>>(counts, starts);

    int gemm_grid = (N + 63) / 64;
    int agg_grid  = (N + 3) / 4;

    // layer 1
    k_gemm<<<gemm_grid, 256, 0, stream>>>(x, w0, dinv, Hs, N, K0);
    k_agg<<<agg_grid, 256, 0, stream>>>(Hs, csr, offs, dinv, b0, h1, N);
    // layer 2
    k_gemm<<<gemm_grid, 256, 0, stream>>>(h1, w1, dinv, Hs, N, HID);
    k_agg<<<agg_grid, 256, 0, stream>>>(Hs, csr, offs, dinv, b1, h2, N);
    // layer 3
    k_gemm<<<gemm_grid, 256, 0, stream>>>(h2, w2, dinv, Hs, N, HID);
    k_agg<<<agg_grid, 256, 0, stream>>>(Hs, csr, offs, dinv, b2, h3, N);
    // layer 4
    k_gemv4<<<(N + 3) / 4, 256, 0, stream>>>(h3, w3, dinv, ts, N);
    k_agg4<<<(N + 255) / 256, 256, 0, stream>>>(ts, csr, offs, dinv, b3, h4, N);

    // sort-pool top-30 per graph
    k_select<<<NGRAPH, 256, 0, stream>>>(h4, starts, counts, sel);

    // tail
    k_tail<<<NGRAPH, 256, 0, stream>>>(h1, h2, h3, h4, sel,
                                       c1w, c1b, c2w, c2b,
                                       l1w, l1b, l2w, l2b,
                                       (float*)d_out);
}

// Round 3
// 363.384 us; speedup vs baseline: 2.5130x; 1.3622x over previous
//
#include <hip/hip_runtime.h>
#include <math.h>

#define NGRAPH 128
#define KTOP 30
#define LATENT 193
#define HID 64

// ---------------- init: edeg=0, cursor=0 ----------------
__global__ void k_init(int* edeg, int* cursor, int n) {
    int i = blockIdx.x * blockDim.x + threadIdx.x;
    if (i < n) { edeg[i] = 0; cursor[i] = 0; }
}

// in-degree histogram over edge dst (edges only, spread atomics)
__global__ void k_hist(const int* __restrict__ dst, int* edeg, int E) {
    int i = blockIdx.x * blockDim.x + threadIdx.x;
    if (i < E) atomicAdd(&edeg[dst[i]], 1);
}

// ---------------- graph starts from SORTED batch (no atomics) ----------------
// starts[g] = first node index of graph g; starts[NGRAPH] = n
__global__ void k_starts(const int* __restrict__ batch, int* starts, int n) {
    int i = blockIdx.x * blockDim.x + threadIdx.x;
    if (i >= n) return;
    int b = batch[i];
    if (i == 0) {
        for (int g = 0; g <= b; g++) starts[g] = 0;
    } else {
        int pb = batch[i - 1];
        for (int g = pb + 1; g <= b; g++) starts[g] = i;
    }
    if (i == n - 1) {
        for (int g = b + 1; g <= NGRAPH; g++) starts[g] = n;
    }
}

// ---------------- hierarchical exclusive scan of edeg -> offs (+ dinv) -------
__global__ void k_scan1(const int* __restrict__ edeg, int* offs, int* bsum,
                        float* dinv, int n) {
    __shared__ int s[256];
    int t = threadIdx.x;
    int gi = blockIdx.x * 256 + t;
    int v = (gi < n) ? edeg[gi] : 0;
    if (gi < n) dinv[gi] = rsqrtf((float)(v + 1));   // +1 self-loop
    s[t] = v;
    __syncthreads();
    for (int o = 1; o < 256; o <<= 1) {
        int add = (t >= o) ? s[t - o] : 0;
        __syncthreads();
        s[t] += add;
        __syncthreads();
    }
    if (gi < n) offs[gi] = s[t] - v;          // local exclusive
    if (t == 255) bsum[blockIdx.x] = s[255];
}

__global__ void k_scan2(int* bsum, int* boff, int nb) {
    __shared__ int s[256];
    int t = threadIdx.x;
    int v = (t < nb) ? bsum[t] : 0;
    s[t] = v;
    __syncthreads();
    for (int o = 1; o < 256; o <<= 1) {
        int add = (t >= o) ? s[t - o] : 0;
        __syncthreads();
        s[t] += add;
        __syncthreads();
    }
    if (t < nb) boff[t] = s[t] - v;
}

__global__ void k_scan3(int* offs, const int* __restrict__ boff, int n, int E) {
    int gi = blockIdx.x * blockDim.x + threadIdx.x;
    if (gi < n) offs[gi] += boff[gi >> 8];
    if (gi == 0) offs[n] = E;
}

// ---------------- fill CSR: csr[offs[dst]+cursor[dst]++] = src ----------------
__global__ void k_fill(const int* __restrict__ src, const int* __restrict__ dst,
                       const int* __restrict__ offs, int* cursor,
                       int* __restrict__ csr, int E) {
    int e = blockIdx.x * blockDim.x + threadIdx.x;
    if (e < E) {
        int d = dst[e];
        int pos = offs[d] + atomicAdd(&cursor[d], 1);
        csr[pos] = src[e];
    }
}

// ---------------- GEMM: Hs = (A @ W) * dinv[row] ----------------
// A: MxK row-major, W: Kx64 row-major. BM=64, BN=64, BK=16, 256 threads, 4x4/thread.
__global__ __launch_bounds__(256) void k_gemm(const float* __restrict__ A,
                                              const float* __restrict__ W,
                                              const float* __restrict__ dinv,
                                              float* __restrict__ Hs,
                                              int M, int K) {
    __shared__ float As[64][17];
    __shared__ float Bs[16][65];
    int tid = threadIdx.x;
    int tx = tid & 15, ty = tid >> 4;
    int br = blockIdx.x * 64;
    float c[4][4] = {};
    for (int k0 = 0; k0 < K; k0 += 16) {
        {   // A tile 64x16
            int idx = tid * 4;
            int r = idx >> 4;
            int kk = idx & 15;
            int grow = br + r;
            float4 v = make_float4(0.f, 0.f, 0.f, 0.f);
            if (grow < M) v = *(const float4*)(A + (size_t)grow * K + k0 + kk);
            As[r][kk + 0] = v.x; As[r][kk + 1] = v.y;
            As[r][kk + 2] = v.z; As[r][kk + 3] = v.w;
        }
        {   // B tile 16x64
            int idx = tid * 4;
            int kk = idx >> 6;
            int col = idx & 63;
            float4 v = *(const float4*)(W + (size_t)(k0 + kk) * 64 + col);
            Bs[kk][col + 0] = v.x; Bs[kk][col + 1] = v.y;
            Bs[kk][col + 2] = v.z; Bs[kk][col + 3] = v.w;
        }
        __syncthreads();
#pragma unroll
        for (int kk = 0; kk < 16; ++kk) {
            float a[4], b[4];
#pragma unroll
            for (int i = 0; i < 4; i++) a[i] = As[ty + i * 16][kk];
#pragma unroll
            for (int j = 0; j < 4; j++) b[j] = Bs[kk][tx + j * 16];
#pragma unroll
            for (int i = 0; i < 4; i++)
#pragma unroll
                for (int j = 0; j < 4; j++) c[i][j] += a[i] * b[j];
        }
        __syncthreads();
    }
#pragma unroll
    for (int i = 0; i < 4; i++) {
        int row = br + ty + i * 16;
        if (row >= M) continue;
        float d = dinv[row];
#pragma unroll
        for (int j = 0; j < 4; j++) {
            int col = tx + j * 16;
            Hs[(size_t)row * HID + col] = c[i][j] * d;
        }
    }
}

// ------- aggregate (gather, wave per node) + fused tanh epilogue -------
// H[n][f] = tanh( (Hs[n][f] + sum_{u in CSR[n]} Hs[u][f]) * dinv[n] + b[f] )
// If FUSE_TS: also ts[n] = (sum_f H[n][f]*w3[f]) * dinv[n]  (layer-4 prescaled GEMV)
template <bool FUSE_TS>
__global__ __launch_bounds__(256) void k_agg(const float* __restrict__ Hs,
                                             const int* __restrict__ csr,
                                             const int* __restrict__ offs,
                                             const float* __restrict__ dinv,
                                             const float* __restrict__ b,
                                             float* __restrict__ H, int n,
                                             const float* __restrict__ w3,
                                             float* __restrict__ ts) {
    int wid = threadIdx.x >> 6;
    int lane = threadIdx.x & 63;
    int node = blockIdx.x * 4 + wid;
    if (node >= n) return;
    float acc = Hs[(size_t)node * HID + lane];     // self-loop term
    int s = offs[node], e = offs[node + 1];
    int i = s;
    for (; i + 4 <= e; i += 4) {
        int u0 = csr[i], u1 = csr[i + 1], u2 = csr[i + 2], u3 = csr[i + 3];
        float v0 = Hs[(size_t)u0 * HID + lane];
        float v1 = Hs[(size_t)u1 * HID + lane];
        float v2 = Hs[(size_t)u2 * HID + lane];
        float v3 = Hs[(size_t)u3 * HID + lane];
        acc += v0 + v1 + v2 + v3;
    }
    for (; i < e; i++) acc += Hs[(size_t)csr[i] * HID + lane];
    float d = dinv[node];
    float h = tanhf(acc * d + b[lane]);
    H[(size_t)node * HID + lane] = h;
    if (FUSE_TS) {
        float v = h * w3[lane];
        for (int o = 32; o > 0; o >>= 1) v += __shfl_down(v, o, 64);
        if (lane == 0) ts[node] = v * d;
    }
}

// layer-4 aggregate + finish: h4 = tanh((ts[n] + sum ts[u]) * dinv[n] + b3)
__global__ void k_agg4(const float* __restrict__ ts, const int* __restrict__ csr,
                       const int* __restrict__ offs, const float* __restrict__ dinv,
                       const float* __restrict__ b3, float* h4, int n) {
    int node = blockIdx.x * blockDim.x + threadIdx.x;
    if (node >= n) return;
    float acc = ts[node];
    int s = offs[node], e = offs[node + 1];
    for (int i = s; i < e; i++) acc += ts[csr[i]];
    h4[node] = tanhf(acc * dinv[node] + b3[0]);
}

// ---------------- top-K selection per graph ----------------
__global__ __launch_bounds__(256) void k_select(const float* __restrict__ h4,
                                                const int* __restrict__ starts,
                                                int* sel) {
    int g = blockIdx.x;
    int s = starts[g], c = starts[g + 1] - s;
    __shared__ float bv[256];
    __shared__ int bi[256];
    __shared__ float pvs;
    __shared__ int pis;
    float pv = 1e30f;
    int pi = -1;
    for (int slot = 0; slot < KTOP; ++slot) {
        float best = -1e30f;
        int bestI = 0x7fffffff;
        for (int i = threadIdx.x; i < c; i += 256) {
            int node = s + i;
            float v = h4[node];
            bool after = (v < pv) || (v == pv && node > pi);
            if (after) {
                if (v > best || (v == best && node < bestI)) { best = v; bestI = node; }
            }
        }
        bv[threadIdx.x] = best;
        bi[threadIdx.x] = bestI;
        __syncthreads();
        for (int o = 128; o > 0; o >>= 1) {
            if (threadIdx.x < o) {
                float v2 = bv[threadIdx.x + o];
                int i2 = bi[threadIdx.x + o];
                if (v2 > bv[threadIdx.x] ||
                    (v2 == bv[threadIdx.x] && i2 < bi[threadIdx.x])) {
                    bv[threadIdx.x] = v2;
                    bi[threadIdx.x] = i2;
                }
            }
            __syncthreads();
        }
        if (threadIdx.x == 0) {
            sel[g * KTOP + slot] = (slot < c) ? bi[0] : -1;
            pvs = bv[0];
            pis = bi[0];
        }
        __syncthreads();
        pv = pvs;
        pi = pis;
        __syncthreads();
    }
}

// ---------------- tail ----------------
__global__ __launch_bounds__(256) void k_tail(const float* __restrict__ h1,
                                              const float* __restrict__ h2,
                                              const float* __restrict__ h3,
                                              const float* __restrict__ h4,
                                              const int* __restrict__ sel,
                                              const float* __restrict__ c1w,
                                              const float* __restrict__ c1b,
                                              const float* __restrict__ c2w,
                                              const float* __restrict__ c2b,
                                              const float* __restrict__ l1w,
                                              const float* __restrict__ l1b,
                                              const float* __restrict__ l2w,
                                              const float* __restrict__ l2b,
                                              float* __restrict__ out) {
    __shared__ float p[KTOP * LATENT];
    __shared__ float w1s[16 * LATENT];
    __shared__ float z1[16 * KTOP];
    __shared__ float z1p[16 * 15];
    __shared__ float w2s[32 * 16 * 5];
    __shared__ float flat[352];
    __shared__ float y1[256];
    int g = blockIdx.x;
    int t = threadIdx.x;
    for (int i = t; i < 16 * LATENT; i += 256) w1s[i] = c1w[i];
    for (int i = t; i < 32 * 16 * 5; i += 256) w2s[i] = c2w[i];
    for (int i = t; i < KTOP * LATENT; i += 256) {
        int slot = i / LATENT;
        int j = i - slot * LATENT;
        int node = sel[g * KTOP + slot];
        float v = 0.f;
        if (node >= 0) {
            if (j < 64)       v = h1[(size_t)node * HID + j];
            else if (j < 128) v = h2[(size_t)node * HID + j - 64];
            else if (j < 192) v = h3[(size_t)node * HID + j - 128];
            else              v = h4[node];
        }
        p[i] = v;
    }
    __syncthreads();
    for (int o = t; o < 16 * KTOP; o += 256) {
        int ch = o / KTOP, tt = o - ch * KTOP;
        float s = c1b[ch];
        const float* wp = &w1s[ch * LATENT];
        const float* pp = &p[tt * LATENT];
        for (int j = 0; j < LATENT; j++) s += pp[j] * wp[j];
        z1[ch * KTOP + tt] = fmaxf(s, 0.f);
    }
    __syncthreads();
    for (int o = t; o < 16 * 15; o += 256) {
        int ch = o / 15, tt = o - ch * 15;
        z1p[o] = fmaxf(z1[ch * KTOP + 2 * tt], z1[ch * KTOP + 2 * tt + 1]);
    }
    __syncthreads();
    for (int o = t; o < 32 * 11; o += 256) {
        int c2 = o / 11, tt = o - c2 * 11;
        float s = c2b[c2];
        for (int c1i = 0; c1i < 16; c1i++) {
            const float* wp = &w2s[(c2 * 16 + c1i) * 5];
            const float* zp = &z1p[c1i * 15 + tt];
#pragma unroll
            for (int dt = 0; dt < 5; dt++) s += zp[dt] * wp[dt];
        }
        flat[c2 * 11 + tt] = fmaxf(s, 0.f);
    }
    __syncthreads();
    {
        float s = l1b[t];
        for (int i = 0; i < 352; i++) s += flat[i] * l1w[i * 256 + t];
        y1[t] = fmaxf(s, 0.f);
    }
    __syncthreads();
    if (t < 2) {
        float s = l2b[t];
        for (int i = 0; i < 256; i++) s += y1[i] * l2w[i * 2 + t];
        out[g * 2 + t] = s;
    }
}

// ---------------- launch ----------------
static inline char* align256(char* p) {
    return (char*)(((uintptr_t)p + 255) & ~(uintptr_t)255);
}

extern "C" void kernel_launch(void* const* d_in, const int* in_sizes, int n_in,
                              void* d_out, int out_size, void* d_ws, size_t ws_size,
                              hipStream_t stream) {
    const float* x     = (const float*)d_in[0];
    const int*  eidx   = (const int*)d_in[1];
    const int*  batch  = (const int*)d_in[2];
    const float* w0    = (const float*)d_in[3];
    const float* b0    = (const float*)d_in[4];
    const float* w1    = (const float*)d_in[5];
    const float* b1    = (const float*)d_in[6];
    const float* w2    = (const float*)d_in[7];
    const float* b2    = (const float*)d_in[8];
    const float* w3    = (const float*)d_in[9];
    const float* b3    = (const float*)d_in[10];
    const float* c1w   = (const float*)d_in[11];
    const float* c1b   = (const float*)d_in[12];
    const float* c2w   = (const float*)d_in[13];
    const float* c2b   = (const float*)d_in[14];
    const float* l1w   = (const float*)d_in[15];
    const float* l1b   = (const float*)d_in[16];
    const float* l2w   = (const float*)d_in[17];
    const float* l2b   = (const float*)d_in[18];

    int N = in_sizes[2];              // 50000 nodes
    int E = in_sizes[1] / 2;          // 800000 edges
    int K0 = in_sizes[0] / N;         // 128 input feats
    const int* esrc = eidx;
    const int* edst = eidx + E;

    char* w = (char*)d_ws;
    float* dinv  = (float*)w;             w = align256(w + (size_t)N * 4);
    int*   edeg  = (int*)w;               w = align256(w + (size_t)N * 4);
    int*   cursor= (int*)w;               w = align256(w + (size_t)N * 4);
    int*   offs  = (int*)w;               w = align256(w + (size_t)(N + 1) * 4);
    int*   bsum  = (int*)w;               w = align256(w + 1024);
    int*   boff  = (int*)w;               w = align256(w + 1024);
    float* ts    = (float*)w;             w = align256(w + (size_t)N * 4);
    float* h4    = (float*)w;             w = align256(w + (size_t)N * 4);
    int* starts  = (int*)w;               w = align256(w + (NGRAPH + 1) * 4);
    int* sel     = (int*)w;               w = align256(w + NGRAPH * KTOP * 4);
    int* csr     = (int*)w;               w = align256(w + (size_t)E * 4);
    float* Hs    = (float*)w;             w = align256(w + (size_t)N * HID * 4);
    float* h1    = (float*)w;             w = align256(w + (size_t)N * HID * 4);
    float* h2    = (float*)w;             w = align256(w + (size_t)N * HID * 4);
    float* h3    = (float*)w;             w = align256(w + (size_t)N * HID * 4);

    int nb = (N + 255) / 256;

    // zero + edge-degree histogram (spread atomics only)
    k_init<<<nb, 256, 0, stream>>>(edeg, cursor, N);
    k_hist<<<(E + 255) / 256, 256, 0, stream>>>(edst, edeg, E);

    // graph starts from sorted batch (no atomics)
    k_starts<<<nb, 256, 0, stream>>>(batch, starts, N);

    // CSR build (scan fused with dinv)
    k_scan1<<<nb, 256, 0, stream>>>(edeg, offs, bsum, dinv, N);
    k_scan2<<<1, 256, 0, stream>>>(bsum, boff, nb);
    k_scan3<<<nb, 256, 0, stream>>>(offs, boff, N, E);
    k_fill<<<(E + 255) / 256, 256, 0, stream>>>(esrc, edst, offs, cursor, csr, E);

    int gemm_grid = (N + 63) / 64;
    int agg_grid  = (N + 3) / 4;

    // layer 1
    k_gemm<<<gemm_grid, 256, 0, stream>>>(x, w0, dinv, Hs, N, K0);
    k_agg<false><<<agg_grid, 256, 0, stream>>>(Hs, csr, offs, dinv, b0, h1, N, nullptr, nullptr);
    // layer 2
    k_gemm<<<gemm_grid, 256, 0, stream>>>(h1, w1, dinv, Hs, N, HID);
    k_agg<false><<<agg_grid, 256, 0, stream>>>(Hs, csr, offs, dinv, b1, h2, N, nullptr, nullptr);
    // layer 3 (+ fused layer-4 prescaled GEMV -> ts)
    k_gemm<<<gemm_grid, 256, 0, stream>>>(h2, w2, dinv, Hs, N, HID);
    k_agg<true><<<agg_grid, 256, 0, stream>>>(Hs, csr, offs, dinv, b2, h3, N, w3, ts);
    // layer 4 aggregate + finish
    k_agg4<<<(N + 255) / 256, 256, 0, stream>>>(ts, csr, offs, dinv, b3, h4, N);

    // sort-pool top-30 per graph
    k_select<<<NGRAPH, 256, 0, stream>>>(h4, starts, sel);

    // tail
    k_tail<<<NGRAPH, 256, 0, stream>>>(h1, h2, h3, h4, sel,
                                       c1w, c1b, c2w, c2b,
                                       l1w, l1b, l2w, l2b,
                                       (float*)d_out);
}

// Round 4
// 302.086 us; speedup vs baseline: 3.0229x; 1.2029x over previous
//
#include <hip/hip_runtime.h>
#include <math.h>

#define NGRAPH 128
#define KTOP 30
#define LATENT 193
#define HID 64

// ---------------- hist (edge in-degree) + graph starts from sorted batch ----
__global__ void k_hist_starts(const int* __restrict__ dst, const int* __restrict__ batch,
                              int* edeg, int* starts, int E, int n) {
    int i = blockIdx.x * blockDim.x + threadIdx.x;
    if (i < E) atomicAdd(&edeg[dst[i]], 1);
    if (i < n) {
        int b = batch[i];
        if (i == 0) {
            for (int g = 0; g <= b; g++) starts[g] = 0;
        } else {
            int pb = batch[i - 1];
            for (int g = pb + 1; g <= b; g++) starts[g] = i;
        }
        if (i == n - 1) {
            for (int g = b + 1; g <= NGRAPH; g++) starts[g] = n;
        }
    }
}

// ---------------- hierarchical exclusive scan of edeg -> offs (+ dinv) -------
__global__ void k_scan1(const int* __restrict__ edeg, int* offs, int* bsum,
                        float* dinv, int n) {
    __shared__ int s[256];
    int t = threadIdx.x;
    int gi = blockIdx.x * 256 + t;
    int v = (gi < n) ? edeg[gi] : 0;
    if (gi < n) dinv[gi] = rsqrtf((float)(v + 1));   // +1 self-loop
    s[t] = v;
    __syncthreads();
    for (int o = 1; o < 256; o <<= 1) {
        int add = (t >= o) ? s[t - o] : 0;
        __syncthreads();
        s[t] += add;
        __syncthreads();
    }
    if (gi < n) offs[gi] = s[t] - v;          // local exclusive
    if (t == 255) bsum[blockIdx.x] = s[255];
}

__global__ void k_scan2(int* bsum, int* boff, int nb) {
    __shared__ int s[256];
    int t = threadIdx.x;
    int v = (t < nb) ? bsum[t] : 0;
    s[t] = v;
    __syncthreads();
    for (int o = 1; o < 256; o <<= 1) {
        int add = (t >= o) ? s[t - o] : 0;
        __syncthreads();
        s[t] += add;
        __syncthreads();
    }
    if (t < nb) boff[t] = s[t] - v;
}

// final offsets + cursor copy (next = offs)
__global__ void k_scan3(int* offs, int* next, const int* __restrict__ boff, int n, int E) {
    int gi = blockIdx.x * blockDim.x + threadIdx.x;
    if (gi < n) {
        int v = offs[gi] + boff[gi >> 8];
        offs[gi] = v;
        next[gi] = v;
    }
    if (gi == 0) offs[n] = E;
}

// ---------------- fused: GEMM (layer 1) + CSR fill, block-interleaved --------
// gemm blocks: Hs = (A @ W) * dinv[row]   (BM=64,BN=64,BK=16, 4x4/thread)
// fill blocks: csr[atomicAdd(&next[dst],1)] = src
__global__ __launch_bounds__(256) void k_gemm_fill(const float* __restrict__ A,
                                                   const float* __restrict__ W,
                                                   const float* __restrict__ dinv,
                                                   float* __restrict__ Hs,
                                                   int M, int K, int NG,
                                                   const int* __restrict__ src,
                                                   const int* __restrict__ dst,
                                                   int* next, int* __restrict__ csr,
                                                   int E) {
    __shared__ float As[64][17];
    __shared__ float Bs[16][65];
    int bid = blockIdx.x;
    int gemm_id = (bid % 5 == 0) ? bid / 5 : -1;
    if (gemm_id >= 0 && gemm_id < NG) {
        int tid = threadIdx.x;
        int tx = tid & 15, ty = tid >> 4;
        int br = gemm_id * 64;
        float c[4][4] = {};
        for (int k0 = 0; k0 < K; k0 += 16) {
            {
                int idx = tid * 4;
                int r = idx >> 4;
                int kk = idx & 15;
                int grow = br + r;
                float4 v = make_float4(0.f, 0.f, 0.f, 0.f);
                if (grow < M) v = *(const float4*)(A + (size_t)grow * K + k0 + kk);
                As[r][kk + 0] = v.x; As[r][kk + 1] = v.y;
                As[r][kk + 2] = v.z; As[r][kk + 3] = v.w;
            }
            {
                int idx = tid * 4;
                int kk = idx >> 6;
                int col = idx & 63;
                float4 v = *(const float4*)(W + (size_t)(k0 + kk) * 64 + col);
                Bs[kk][col + 0] = v.x; Bs[kk][col + 1] = v.y;
                Bs[kk][col + 2] = v.z; Bs[kk][col + 3] = v.w;
            }
            __syncthreads();
#pragma unroll
            for (int kk = 0; kk < 16; ++kk) {
                float a[4], b[4];
#pragma unroll
                for (int i = 0; i < 4; i++) a[i] = As[ty + i * 16][kk];
#pragma unroll
                for (int j = 0; j < 4; j++) b[j] = Bs[kk][tx + j * 16];
#pragma unroll
                for (int i = 0; i < 4; i++)
#pragma unroll
                    for (int j = 0; j < 4; j++) c[i][j] += a[i] * b[j];
            }
            __syncthreads();
        }
#pragma unroll
        for (int i = 0; i < 4; i++) {
            int row = br + ty + i * 16;
            if (row >= M) continue;
            float d = dinv[row];
#pragma unroll
            for (int j = 0; j < 4; j++) {
                int col = tx + j * 16;
                Hs[(size_t)row * HID + col] = c[i][j] * d;
            }
        }
    } else {
        // fill block id = bid minus # of gemm bids < bid
        int ngb = min((bid + 4) / 5, NG);
        int fid = bid - ngb;
        int e = fid * 256 + threadIdx.x;
        if (e < E) {
            int d = dst[e];
            int pos = atomicAdd(&next[d], 1);
            csr[pos] = src[e];
        }
    }
}

// ---------------- plain GEMM (layers 2,3) ----------------
__global__ __launch_bounds__(256) void k_gemm(const float* __restrict__ A,
                                              const float* __restrict__ W,
                                              const float* __restrict__ dinv,
                                              float* __restrict__ Hs,
                                              int M, int K) {
    __shared__ float As[64][17];
    __shared__ float Bs[16][65];
    int tid = threadIdx.x;
    int tx = tid & 15, ty = tid >> 4;
    int br = blockIdx.x * 64;
    float c[4][4] = {};
    for (int k0 = 0; k0 < K; k0 += 16) {
        {
            int idx = tid * 4;
            int r = idx >> 4;
            int kk = idx & 15;
            int grow = br + r;
            float4 v = make_float4(0.f, 0.f, 0.f, 0.f);
            if (grow < M) v = *(const float4*)(A + (size_t)grow * K + k0 + kk);
            As[r][kk + 0] = v.x; As[r][kk + 1] = v.y;
            As[r][kk + 2] = v.z; As[r][kk + 3] = v.w;
        }
        {
            int idx = tid * 4;
            int kk = idx >> 6;
            int col = idx & 63;
            float4 v = *(const float4*)(W + (size_t)(k0 + kk) * 64 + col);
            Bs[kk][col + 0] = v.x; Bs[kk][col + 1] = v.y;
            Bs[kk][col + 2] = v.z; Bs[kk][col + 3] = v.w;
        }
        __syncthreads();
#pragma unroll
        for (int kk = 0; kk < 16; ++kk) {
            float a[4], b[4];
#pragma unroll
            for (int i = 0; i < 4; i++) a[i] = As[ty + i * 16][kk];
#pragma unroll
            for (int j = 0; j < 4; j++) b[j] = Bs[kk][tx + j * 16];
#pragma unroll
            for (int i = 0; i < 4; i++)
#pragma unroll
                for (int j = 0; j < 4; j++) c[i][j] += a[i] * b[j];
        }
        __syncthreads();
    }
#pragma unroll
    for (int i = 0; i < 4; i++) {
        int row = br + ty + i * 16;
        if (row >= M) continue;
        float d = dinv[row];
#pragma unroll
        for (int j = 0; j < 4; j++) {
            int col = tx + j * 16;
            Hs[(size_t)row * HID + col] = c[i][j] * d;
        }
    }
}

// ------- aggregate (gather, wave per node) + fused tanh epilogue -------
template <bool FUSE_TS>
__global__ __launch_bounds__(256) void k_agg(const float* __restrict__ Hs,
                                             const int* __restrict__ csr,
                                             const int* __restrict__ offs,
                                             const float* __restrict__ dinv,
                                             const float* __restrict__ b,
                                             float* __restrict__ H, int n,
                                             const float* __restrict__ w3,
                                             float* __restrict__ ts) {
    int wid = threadIdx.x >> 6;
    int lane = threadIdx.x & 63;
    int node = blockIdx.x * 4 + wid;
    if (node >= n) return;
    float acc = Hs[(size_t)node * HID + lane];     // self-loop term
    int s = offs[node], e = offs[node + 1];
    int i = s;
    for (; i + 4 <= e; i += 4) {
        int u0 = csr[i], u1 = csr[i + 1], u2 = csr[i + 2], u3 = csr[i + 3];
        float v0 = Hs[(size_t)u0 * HID + lane];
        float v1 = Hs[(size_t)u1 * HID + lane];
        float v2 = Hs[(size_t)u2 * HID + lane];
        float v3 = Hs[(size_t)u3 * HID + lane];
        acc += v0 + v1 + v2 + v3;
    }
    for (; i < e; i++) acc += Hs[(size_t)csr[i] * HID + lane];
    float d = dinv[node];
    float h = tanhf(acc * d + b[lane]);
    H[(size_t)node * HID + lane] = h;
    if (FUSE_TS) {
        float v = h * w3[lane];
        for (int o = 32; o > 0; o >>= 1) v += __shfl_down(v, o, 64);
        if (lane == 0) ts[node] = v * d;
    }
}

// layer-4 aggregate + finish
__global__ void k_agg4(const float* __restrict__ ts, const int* __restrict__ csr,
                       const int* __restrict__ offs, const float* __restrict__ dinv,
                       const float* __restrict__ b3, float* h4, int n) {
    int node = blockIdx.x * blockDim.x + threadIdx.x;
    if (node >= n) return;
    float acc = ts[node];
    int s = offs[node], e = offs[node + 1];
    for (int i = s; i < e; i++) acc += ts[csr[i]];
    h4[node] = tanhf(acc * dinv[node] + b3[0]);
}

// ---------------- single-pass rank-based top-K selection ----------------
// rank_i = #{j : v_j > v_i  or (v_j == v_i and j < i)}  == stable desc order
__global__ __launch_bounds__(512) void k_select(const float* __restrict__ h4,
                                                const int* __restrict__ starts,
                                                int* __restrict__ sel) {
    int g = blockIdx.x;
    int s = starts[g], c = starts[g + 1] - s;
    __shared__ float v[1024];
    int t = threadIdx.x;
    if (c <= 1024) {
        for (int i = t; i < c; i += 512) v[i] = h4[s + i];
        __syncthreads();
        for (int i = t; i < c; i += 512) {
            float vi = v[i];
            int r = 0;
            for (int j = 0; j < c; j++) {
                float vj = v[j];
                r += (vj > vi) || (vj == vi && j < i);
            }
            if (r < KTOP) sel[g * KTOP + r] = s + i;
        }
    } else {
        for (int i = t; i < c; i += 512) {
            float vi = h4[s + i];
            int r = 0;
            for (int j = 0; j < c; j++) {
                float vj = h4[s + j];
                r += (vj > vi) || (vj == vi && j < i);
            }
            if (r < KTOP) sel[g * KTOP + r] = s + i;
        }
    }
    for (int slot = t; slot < KTOP; slot += 512)
        if (slot >= c) sel[g * KTOP + slot] = -1;
}

// ---------------- tail: 1024 threads / graph ----------------
__global__ __launch_bounds__(1024) void k_tail(const float* __restrict__ h1,
                                               const float* __restrict__ h2,
                                               const float* __restrict__ h3,
                                               const float* __restrict__ h4,
                                               const int* __restrict__ sel,
                                               const float* __restrict__ c1w,
                                               const float* __restrict__ c1b,
                                               const float* __restrict__ c2w,
                                               const float* __restrict__ c2b,
                                               const float* __restrict__ l1w,
                                               const float* __restrict__ l1b,
                                               const float* __restrict__ l2w,
                                               const float* __restrict__ l2b,
                                               float* __restrict__ out) {
    __shared__ float p[KTOP * LATENT];    // 5790
    __shared__ float w1s[16 * LATENT];    // 3088
    __shared__ float w2s[32 * 16 * 5];    // 2560
    __shared__ float z1[16 * KTOP];       // 480
    __shared__ float z1p[16 * 15];        // 240
    __shared__ float flat[352];
    __shared__ float part[1024];
    __shared__ float y1[256];
    int g = blockIdx.x;
    int t = threadIdx.x;
    for (int i = t; i < 16 * LATENT; i += 1024) w1s[i] = c1w[i];
    for (int i = t; i < 32 * 16 * 5; i += 1024) w2s[i] = c2w[i];
    for (int i = t; i < KTOP * LATENT; i += 1024) {
        int slot = i / LATENT;
        int j = i - slot * LATENT;
        int node = sel[g * KTOP + slot];
        float v = 0.f;
        if (node >= 0) {
            if (j < 64)       v = h1[(size_t)node * HID + j];
            else if (j < 128) v = h2[(size_t)node * HID + j - 64];
            else if (j < 192) v = h3[(size_t)node * HID + j - 128];
            else              v = h4[node];
        }
        p[i] = v;
    }
    __syncthreads();
    // conv1 (per-slot linear 193->16) + relu : 480 outputs
    if (t < 16 * KTOP) {
        int ch = t / KTOP, tt = t - ch * KTOP;
        float s = c1b[ch];
        const float* wp = &w1s[ch * LATENT];
        const float* pp = &p[tt * LATENT];
        for (int j = 0; j < LATENT; j++) s += pp[j] * wp[j];
        z1[ch * KTOP + tt] = fmaxf(s, 0.f);
    }
    __syncthreads();
    // maxpool pairs 30->15 : 240 outputs
    if (t < 16 * 15) {
        int ch = t / 15, tt = t - ch * 15;
        z1p[t] = fmaxf(z1[ch * KTOP + 2 * tt], z1[ch * KTOP + 2 * tt + 1]);
    }
    __syncthreads();
    // conv2 16x5 -> 32ch, len 11 : 352 outputs
    if (t < 32 * 11) {
        int c2 = t / 11, tt = t - c2 * 11;
        float s = c2b[c2];
        for (int c1i = 0; c1i < 16; c1i++) {
            const float* wp = &w2s[(c2 * 16 + c1i) * 5];
            const float* zp = &z1p[c1i * 15 + tt];
#pragma unroll
            for (int dt = 0; dt < 5; dt++) s += zp[dt] * wp[dt];
        }
        flat[c2 * 11 + tt] = fmaxf(s, 0.f);
    }
    __syncthreads();
    // lin1 352->256, 4-way K-split
    {
        int o = t & 255, ch = t >> 8;
        int i0 = ch * 88, i1 = i0 + 88;
        float s = 0.f;
        for (int i = i0; i < i1; i++) s += flat[i] * l1w[(size_t)i * 256 + o];
        part[t] = s;
    }
    __syncthreads();
    if (t < 256)
        y1[t] = fmaxf(part[t] + part[256 + t] + part[512 + t] + part[768 + t] + l1b[t], 0.f);
    __syncthreads();
    // lin2 256->2 : wave per output
    if (t < 128) {
        int o = t >> 6, lane = t & 63;
        float s = 0.f;
        for (int i = lane; i < 256; i += 64) s += y1[i] * l2w[(size_t)i * 2 + o];
        for (int off = 32; off > 0; off >>= 1) s += __shfl_down(s, off, 64);
        if (lane == 0) out[g * 2 + o] = s + l2b[o];
    }
}

// ---------------- launch ----------------
static inline char* align256(char* p) {
    return (char*)(((uintptr_t)p + 255) & ~(uintptr_t)255);
}

extern "C" void kernel_launch(void* const* d_in, const int* in_sizes, int n_in,
                              void* d_out, int out_size, void* d_ws, size_t ws_size,
                              hipStream_t stream) {
    const float* x     = (const float*)d_in[0];
    const int*  eidx   = (const int*)d_in[1];
    const int*  batch  = (const int*)d_in[2];
    const float* w0    = (const float*)d_in[3];
    const float* b0    = (const float*)d_in[4];
    const float* w1    = (const float*)d_in[5];
    const float* b1    = (const float*)d_in[6];
    const float* w2    = (const float*)d_in[7];
    const float* b2    = (const float*)d_in[8];
    const float* w3    = (const float*)d_in[9];
    const float* b3    = (const float*)d_in[10];
    const float* c1w   = (const float*)d_in[11];
    const float* c1b   = (const float*)d_in[12];
    const float* c2w   = (const float*)d_in[13];
    const float* c2b   = (const float*)d_in[14];
    const float* l1w   = (const float*)d_in[15];
    const float* l1b   = (const float*)d_in[16];
    const float* l2w   = (const float*)d_in[17];
    const float* l2b   = (const float*)d_in[18];

    int N = in_sizes[2];              // 50000 nodes
    int E = in_sizes[1] / 2;          // 800000 edges
    int K0 = in_sizes[0] / N;         // 128 input feats
    const int* esrc = eidx;
    const int* edst = eidx + E;

    char* w = (char*)d_ws;
    float* dinv  = (float*)w;             w = align256(w + (size_t)N * 4);
    int*   edeg  = (int*)w;               w = align256(w + (size_t)N * 4);
    int*   next  = (int*)w;               w = align256(w + (size_t)N * 4);
    int*   offs  = (int*)w;               w = align256(w + (size_t)(N + 1) * 4);
    int*   bsum  = (int*)w;               w = align256(w + 1024);
    int*   boff  = (int*)w;               w = align256(w + 1024);
    float* ts    = (float*)w;             w = align256(w + (size_t)N * 4);
    float* h4    = (float*)w;             w = align256(w + (size_t)N * 4);
    int* starts  = (int*)w;               w = align256(w + (NGRAPH + 1) * 4);
    int* sel     = (int*)w;               w = align256(w + NGRAPH * KTOP * 4);
    int* csr     = (int*)w;               w = align256(w + (size_t)E * 4);
    float* Hs    = (float*)w;             w = align256(w + (size_t)N * HID * 4);
    float* h1    = (float*)w;             w = align256(w + (size_t)N * HID * 4);
    float* h2    = (float*)w;             w = align256(w + (size_t)N * HID * 4);
    float* h3    = (float*)w;             w = align256(w + (size_t)N * HID * 4);

    int nb = (N + 255) / 256;

    // zero degree array
    hipMemsetAsync(edeg, 0, (size_t)N * 4, stream);

    // edge-degree histogram + graph starts (fused)
    k_hist_starts<<<(E + 255) / 256, 256, 0, stream>>>(edst, batch, edeg, starts, E, N);

    // CSR offsets (scan fused with dinv), next = offs copy
    k_scan1<<<nb, 256, 0, stream>>>(edeg, offs, bsum, dinv, N);
    k_scan2<<<1, 256, 0, stream>>>(bsum, boff, nb);
    k_scan3<<<nb, 256, 0, stream>>>(offs, next, boff, N, E);

    int NG = (N + 63) / 64;
    int NF = (E + 255) / 256;
    int agg_grid = (N + 3) / 4;

    // layer-1 GEMM overlapped with CSR fill (block-interleaved)
    k_gemm_fill<<<NG + NF, 256, 0, stream>>>(x, w0, dinv, Hs, N, K0, NG,
                                             esrc, edst, next, csr, E);
    k_agg<false><<<agg_grid, 256, 0, stream>>>(Hs, csr, offs, dinv, b0, h1, N, nullptr, nullptr);
    // layer 2
    k_gemm<<<NG, 256, 0, stream>>>(h1, w1, dinv, Hs, N, HID);
    k_agg<false><<<agg_grid, 256, 0, stream>>>(Hs, csr, offs, dinv, b1, h2, N, nullptr, nullptr);
    // layer 3 (+ fused layer-4 prescaled GEMV -> ts)
    k_gemm<<<NG, 256, 0, stream>>>(h2, w2, dinv, Hs, N, HID);
    k_agg<true><<<agg_grid, 256, 0, stream>>>(Hs, csr, offs, dinv, b2, h3, N, w3, ts);
    // layer 4 aggregate + finish
    k_agg4<<<(N + 255) / 256, 256, 0, stream>>>(ts, csr, offs, dinv, b3, h4, N);

    // sort-pool top-30 per graph (single-pass rank select)
    k_select<<<NGRAPH, 512, 0, stream>>>(h4, starts, sel);

    // tail
    k_tail<<<NGRAPH, 1024, 0, stream>>>(h1, h2, h3, h4, sel,
                                        c1w, c1b, c2w, c2b,
                                        l1w, l1b, l2w, l2b,
                                        (float*)d_out);
}

// Round 5
// 262.398 us; speedup vs baseline: 3.4801x; 1.1513x over previous
//
#include <hip/hip_runtime.h>
#include <math.h>

#define NGRAPH 128
#define KTOP 30
#define LATENT 193
#define HID 64

typedef unsigned short u16;

// ---- K1: fused layer-1 GEMM (raw, no dinv) + edge hist/rank + graph starts ----
// even blocks: Hs_raw = A @ W  (BM=64,BN=64,BK=16, 4x4/thread)
// odd  blocks: rank[e] = atomicAdd(&edeg[dst[e]],1); starts from sorted batch
__global__ __launch_bounds__(256) void k_gemm_hist(
        const float* __restrict__ A, const float* __restrict__ W,
        float* __restrict__ Hs, int M, int K, int NG,
        const int* __restrict__ dst, const int* __restrict__ batch,
        int* edeg, u16* __restrict__ rank, int* starts,
        int E, int n, int NH) {
    __shared__ float As[64][17];
    __shared__ float Bs[16][65];
    int bid = blockIdx.x;
    if ((bid & 1) == 0) {
        int gemm_id = bid >> 1;
        if (gemm_id >= NG) return;
        int tid = threadIdx.x;
        int tx = tid & 15, ty = tid >> 4;
        int br = gemm_id * 64;
        float c[4][4] = {};
        for (int k0 = 0; k0 < K; k0 += 16) {
            {
                int idx = tid * 4;
                int r = idx >> 4;
                int kk = idx & 15;
                int grow = br + r;
                float4 v = make_float4(0.f, 0.f, 0.f, 0.f);
                if (grow < M) v = *(const float4*)(A + (size_t)grow * K + k0 + kk);
                As[r][kk + 0] = v.x; As[r][kk + 1] = v.y;
                As[r][kk + 2] = v.z; As[r][kk + 3] = v.w;
            }
            {
                int idx = tid * 4;
                int kk = idx >> 6;
                int col = idx & 63;
                float4 v = *(const float4*)(W + (size_t)(k0 + kk) * 64 + col);
                Bs[kk][col + 0] = v.x; Bs[kk][col + 1] = v.y;
                Bs[kk][col + 2] = v.z; Bs[kk][col + 3] = v.w;
            }
            __syncthreads();
#pragma unroll
            for (int kk = 0; kk < 16; ++kk) {
                float a[4], b[4];
#pragma unroll
                for (int i = 0; i < 4; i++) a[i] = As[ty + i * 16][kk];
#pragma unroll
                for (int j = 0; j < 4; j++) b[j] = Bs[kk][tx + j * 16];
#pragma unroll
                for (int i = 0; i < 4; i++)
#pragma unroll
                    for (int j = 0; j < 4; j++) c[i][j] += a[i] * b[j];
            }
            __syncthreads();
        }
#pragma unroll
        for (int i = 0; i < 4; i++) {
            int row = br + ty + i * 16;
            if (row >= M) continue;
#pragma unroll
            for (int j = 0; j < 4; j++) {
                int col = tx + j * 16;
                Hs[(size_t)row * HID + col] = c[i][j];   // raw (dinv deferred)
            }
        }
    } else {
        int fid = bid >> 1;
        if (fid >= NH) return;
        int t = threadIdx.x;
        int gi = fid * 256 + t;
        if (gi < n) {
            int b = batch[gi];
            if (gi == 0) {
                for (int g = 0; g <= b; g++) starts[g] = 0;
            } else {
                int pb = batch[gi - 1];
                for (int g = pb + 1; g <= b; g++) starts[g] = gi;
            }
            if (gi == n - 1) {
                for (int g = b + 1; g <= NGRAPH; g++) starts[g] = n;
            }
        }
        int base = fid * 1024;
#pragma unroll
        for (int k = 0; k < 4; k++) {
            int e = base + k * 256 + t;
            if (e < E) {
                int d = dst[e];
                rank[e] = (u16)atomicAdd(&edeg[d], 1);
            }
        }
    }
}

// ---------------- hierarchical exclusive scan of edeg -> offs (+ dinv) -------
__global__ void k_scan1(const int* __restrict__ edeg, int* offs, int* bsum,
                        float* dinv, int n) {
    __shared__ int s[256];
    int t = threadIdx.x;
    int gi = blockIdx.x * 256 + t;
    int v = (gi < n) ? edeg[gi] : 0;
    if (gi < n) dinv[gi] = rsqrtf((float)(v + 1));   // +1 self-loop
    s[t] = v;
    __syncthreads();
    for (int o = 1; o < 256; o <<= 1) {
        int add = (t >= o) ? s[t - o] : 0;
        __syncthreads();
        s[t] += add;
        __syncthreads();
    }
    if (gi < n) offs[gi] = s[t] - v;          // local exclusive
    if (t == 255) bsum[blockIdx.x] = s[255];
}

__global__ void k_scan2(int* bsum, int* boff, int nb) {
    __shared__ int s[256];
    int t = threadIdx.x;
    int v = (t < nb) ? bsum[t] : 0;
    s[t] = v;
    __syncthreads();
    for (int o = 1; o < 256; o <<= 1) {
        int add = (t >= o) ? s[t - o] : 0;
        __syncthreads();
        s[t] += add;
        __syncthreads();
    }
    if (t < nb) boff[t] = s[t] - v;
}

__global__ void k_scan3(int* offs, const int* __restrict__ boff, int n, int E) {
    int gi = blockIdx.x * blockDim.x + threadIdx.x;
    if (gi < n) offs[gi] += boff[gi >> 8];
    if (gi == 0) offs[n] = E;
}

// ---------------- CSR fill, NO atomics: csr[offs[dst]+rank] = src ------------
__global__ __launch_bounds__(256) void k_fill(const int* __restrict__ src,
                                              const int* __restrict__ dst,
                                              const u16* __restrict__ rank,
                                              const int* __restrict__ offs,
                                              u16* __restrict__ csr, int E) {
    int t = blockIdx.x * 256 + threadIdx.x;
    int e0 = t * 4;
    if (e0 + 4 <= E) {
        int4 s4 = *(const int4*)(src + e0);
        int4 d4 = *(const int4*)(dst + e0);
        const u16* rp = rank + e0;
        csr[offs[d4.x] + rp[0]] = (u16)s4.x;
        csr[offs[d4.y] + rp[1]] = (u16)s4.y;
        csr[offs[d4.z] + rp[2]] = (u16)s4.z;
        csr[offs[d4.w] + rp[3]] = (u16)s4.w;
    } else {
        for (int e = e0; e < E; e++)
            csr[offs[dst[e]] + rank[e]] = (u16)src[e];
    }
}

// ---------------- plain GEMM (layers 2,3): Hs = (A @ W) * dinv[row] ----------
__global__ __launch_bounds__(256) void k_gemm(const float* __restrict__ A,
                                              const float* __restrict__ W,
                                              const float* __restrict__ dinv,
                                              float* __restrict__ Hs,
                                              int M, int K) {
    __shared__ float As[64][17];
    __shared__ float Bs[16][65];
    int tid = threadIdx.x;
    int tx = tid & 15, ty = tid >> 4;
    int br = blockIdx.x * 64;
    float c[4][4] = {};
    for (int k0 = 0; k0 < K; k0 += 16) {
        {
            int idx = tid * 4;
            int r = idx >> 4;
            int kk = idx & 15;
            int grow = br + r;
            float4 v = make_float4(0.f, 0.f, 0.f, 0.f);
            if (grow < M) v = *(const float4*)(A + (size_t)grow * K + k0 + kk);
            As[r][kk + 0] = v.x; As[r][kk + 1] = v.y;
            As[r][kk + 2] = v.z; As[r][kk + 3] = v.w;
        }
        {
            int idx = tid * 4;
            int kk = idx >> 6;
            int col = idx & 63;
            float4 v = *(const float4*)(W + (size_t)(k0 + kk) * 64 + col);
            Bs[kk][col + 0] = v.x; Bs[kk][col + 1] = v.y;
            Bs[kk][col + 2] = v.z; Bs[kk][col + 3] = v.w;
        }
        __syncthreads();
#pragma unroll
        for (int kk = 0; kk < 16; ++kk) {
            float a[4], b[4];
#pragma unroll
            for (int i = 0; i < 4; i++) a[i] = As[ty + i * 16][kk];
#pragma unroll
            for (int j = 0; j < 4; j++) b[j] = Bs[kk][tx + j * 16];
#pragma unroll
            for (int i = 0; i < 4; i++)
#pragma unroll
                for (int j = 0; j < 4; j++) c[i][j] += a[i] * b[j];
        }
        __syncthreads();
    }
#pragma unroll
    for (int i = 0; i < 4; i++) {
        int row = br + ty + i * 16;
        if (row >= M) continue;
        float d = dinv[row];
#pragma unroll
        for (int j = 0; j < 4; j++) {
            int col = tx + j * 16;
            Hs[(size_t)row * HID + col] = c[i][j] * d;
        }
    }
}

// ------- aggregate (gather, wave per node) + fused tanh epilogue -------
// DEFER: Hs is raw (layer 1) -> multiply each gathered row by dinv[u]
template <bool DEFER, bool FUSE_TS>
__global__ __launch_bounds__(256) void k_agg(const float* __restrict__ Hs,
                                             const u16* __restrict__ csr,
                                             const int* __restrict__ offs,
                                             const float* __restrict__ dinv,
                                             const float* __restrict__ b,
                                             float* __restrict__ H, int n,
                                             const float* __restrict__ w3,
                                             float* __restrict__ ts) {
    int wid = threadIdx.x >> 6;
    int lane = threadIdx.x & 63;
    int node = blockIdx.x * 4 + wid;
    if (node >= n) return;
    float d = dinv[node];
    float acc = Hs[(size_t)node * HID + lane];
    if (DEFER) acc *= d;
    int s = offs[node], e = offs[node + 1];
    int i = s;
    for (; i + 8 <= e; i += 8) {
        float part = 0.f;
#pragma unroll
        for (int k = 0; k < 8; k++) {
            int u = csr[i + k];
            float v = Hs[(size_t)u * HID + lane];
            if (DEFER) v *= dinv[u];
            part += v;
        }
        acc += part;
    }
    for (; i < e; i++) {
        int u = csr[i];
        float v = Hs[(size_t)u * HID + lane];
        if (DEFER) v *= dinv[u];
        acc += v;
    }
    float h = tanhf(acc * d + b[lane]);
    H[(size_t)node * HID + lane] = h;
    if (FUSE_TS) {
        float v = h * w3[lane];
        for (int o = 32; o > 0; o >>= 1) v += __shfl_down(v, o, 64);
        if (lane == 0) ts[node] = v * d;
    }
}

// layer-4 aggregate + finish
__global__ void k_agg4(const float* __restrict__ ts, const u16* __restrict__ csr,
                       const int* __restrict__ offs, const float* __restrict__ dinv,
                       const float* __restrict__ b3, float* h4, int n) {
    int node = blockIdx.x * blockDim.x + threadIdx.x;
    if (node >= n) return;
    float acc = ts[node];
    int s = offs[node], e = offs[node + 1];
    for (int i = s; i < e; i++) acc += ts[csr[i]];
    h4[node] = tanhf(acc * dinv[node] + b3[0]);
}

// ---------------- single-pass rank-based top-K selection ----------------
__global__ __launch_bounds__(512) void k_select(const float* __restrict__ h4,
                                                const int* __restrict__ starts,
                                                int* __restrict__ sel) {
    int g = blockIdx.x;
    int s = starts[g], c = starts[g + 1] - s;
    __shared__ float v[1024];
    int t = threadIdx.x;
    if (c <= 1024) {
        for (int i = t; i < c; i += 512) v[i] = h4[s + i];
        __syncthreads();
        for (int i = t; i < c; i += 512) {
            float vi = v[i];
            int r = 0;
            for (int j = 0; j < c; j++) {
                float vj = v[j];
                r += (vj > vi) || (vj == vi && j < i);
            }
            if (r < KTOP) sel[g * KTOP + r] = s + i;
        }
    } else {
        for (int i = t; i < c; i += 512) {
            float vi = h4[s + i];
            int r = 0;
            for (int j = 0; j < c; j++) {
                float vj = h4[s + j];
                r += (vj > vi) || (vj == vi && j < i);
            }
            if (r < KTOP) sel[g * KTOP + r] = s + i;
        }
    }
    for (int slot = t; slot < KTOP; slot += 512)
        if (slot >= c) sel[g * KTOP + slot] = -1;
}

// ---------------- tail: 1024 threads / graph ----------------
__global__ __launch_bounds__(1024) void k_tail(const float* __restrict__ h1,
                                               const float* __restrict__ h2,
                                               const float* __restrict__ h3,
                                               const float* __restrict__ h4,
                                               const int* __restrict__ sel,
                                               const float* __restrict__ c1w,
                                               const float* __restrict__ c1b,
                                               const float* __restrict__ c2w,
                                               const float* __restrict__ c2b,
                                               const float* __restrict__ l1w,
                                               const float* __restrict__ l1b,
                                               const float* __restrict__ l2w,
                                               const float* __restrict__ l2b,
                                               float* __restrict__ out) {
    __shared__ float p[KTOP * LATENT];
    __shared__ float w1s[16 * LATENT];
    __shared__ float w2s[32 * 16 * 5];
    __shared__ float z1[16 * KTOP];
    __shared__ float z1p[16 * 15];
    __shared__ float flat[352];
    __shared__ float part[1024];
    __shared__ float y1[256];
    int g = blockIdx.x;
    int t = threadIdx.x;
    for (int i = t; i < 16 * LATENT; i += 1024) w1s[i] = c1w[i];
    for (int i = t; i < 32 * 16 * 5; i += 1024) w2s[i] = c2w[i];
    for (int i = t; i < KTOP * LATENT; i += 1024) {
        int slot = i / LATENT;
        int j = i - slot * LATENT;
        int node = sel[g * KTOP + slot];
        float v = 0.f;
        if (node >= 0) {
            if (j < 64)       v = h1[(size_t)node * HID + j];
            else if (j < 128) v = h2[(size_t)node * HID + j - 64];
            else if (j < 192) v = h3[(size_t)node * HID + j - 128];
            else              v = h4[node];
        }
        p[i] = v;
    }
    __syncthreads();
    if (t < 16 * KTOP) {
        int ch = t / KTOP, tt = t - ch * KTOP;
        float s = c1b[ch];
        const float* wp = &w1s[ch * LATENT];
        const float* pp = &p[tt * LATENT];
        for (int j = 0; j < LATENT; j++) s += pp[j] * wp[j];
        z1[ch * KTOP + tt] = fmaxf(s, 0.f);
    }
    __syncthreads();
    if (t < 16 * 15) {
        int ch = t / 15, tt = t - ch * 15;
        z1p[t] = fmaxf(z1[ch * KTOP + 2 * tt], z1[ch * KTOP + 2 * tt + 1]);
    }
    __syncthreads();
    if (t < 32 * 11) {
        int c2 = t / 11, tt = t - c2 * 11;
        float s = c2b[c2];
        for (int c1i = 0; c1i < 16; c1i++) {
            const float* wp = &w2s[(c2 * 16 + c1i) * 5];
            const float* zp = &z1p[c1i * 15 + tt];
#pragma unroll
            for (int dt = 0; dt < 5; dt++) s += zp[dt] * wp[dt];
        }
        flat[c2 * 11 + tt] = fmaxf(s, 0.f);
    }
    __syncthreads();
    {
        int o = t & 255, ch = t >> 8;
        int i0 = ch * 88, i1 = i0 + 88;
        float s = 0.f;
        for (int i = i0; i < i1; i++) s += flat[i] * l1w[(size_t)i * 256 + o];
        part[t] = s;
    }
    __syncthreads();
    if (t < 256)
        y1[t] = fmaxf(part[t] + part[256 + t] + part[512 + t] + part[768 + t] + l1b[t], 0.f);
    __syncthreads();
    if (t < 128) {
        int o = t >> 6, lane = t & 63;
        float s = 0.f;
        for (int i = lane; i < 256; i += 64) s += y1[i] * l2w[(size_t)i * 2 + o];
        for (int off = 32; off > 0; off >>= 1) s += __shfl_down(s, off, 64);
        if (lane == 0) out[g * 2 + o] = s + l2b[o];
    }
}

// ---------------- launch ----------------
static inline char* align256(char* p) {
    return (char*)(((uintptr_t)p + 255) & ~(uintptr_t)255);
}

extern "C" void kernel_launch(void* const* d_in, const int* in_sizes, int n_in,
                              void* d_out, int out_size, void* d_ws, size_t ws_size,
                              hipStream_t stream) {
    const float* x     = (const float*)d_in[0];
    const int*  eidx   = (const int*)d_in[1];
    const int*  batch  = (const int*)d_in[2];
    const float* w0    = (const float*)d_in[3];
    const float* b0    = (const float*)d_in[4];
    const float* w1    = (const float*)d_in[5];
    const float* b1    = (const float*)d_in[6];
    const float* w2    = (const float*)d_in[7];
    const float* b2    = (const float*)d_in[8];
    const float* w3    = (const float*)d_in[9];
    const float* b3    = (const float*)d_in[10];
    const float* c1w   = (const float*)d_in[11];
    const float* c1b   = (const float*)d_in[12];
    const float* c2w   = (const float*)d_in[13];
    const float* c2b   = (const float*)d_in[14];
    const float* l1w   = (const float*)d_in[15];
    const float* l1b   = (const float*)d_in[16];
    const float* l2w   = (const float*)d_in[17];
    const float* l2b   = (const float*)d_in[18];

    int N = in_sizes[2];              // 50000 nodes
    int E = in_sizes[1] / 2;          // 800000 edges
    int K0 = in_sizes[0] / N;         // 128 input feats
    const int* esrc = eidx;
    const int* edst = eidx + E;

    char* w = (char*)d_ws;
    float* dinv  = (float*)w;             w = align256(w + (size_t)N * 4);
    int*   edeg  = (int*)w;               w = align256(w + (size_t)N * 4);
    int*   offs  = (int*)w;               w = align256(w + (size_t)(N + 1) * 4);
    int*   bsum  = (int*)w;               w = align256(w + 1024);
    int*   boff  = (int*)w;               w = align256(w + 1024);
    float* ts    = (float*)w;             w = align256(w + (size_t)N * 4);
    float* h4    = (float*)w;             w = align256(w + (size_t)N * 4);
    int* starts  = (int*)w;               w = align256(w + (NGRAPH + 1) * 4);
    int* sel     = (int*)w;               w = align256(w + NGRAPH * KTOP * 4);
    u16* rank    = (u16*)w;               w = align256(w + (size_t)E * 2);
    u16* csr     = (u16*)w;               w = align256(w + (size_t)E * 2);
    float* Hs    = (float*)w;             w = align256(w + (size_t)N * HID * 4);
    float* h1    = (float*)w;             w = align256(w + (size_t)N * HID * 4);
    float* h2    = (float*)w;             w = align256(w + (size_t)N * HID * 4);
    float* h3    = (float*)w;             w = align256(w + (size_t)N * HID * 4);

    int nb = (N + 255) / 256;
    int NG = (N + 63) / 64;
    int NH = (E + 1023) / 1024;
    int agg_grid = (N + 3) / 4;

    // zero degree array
    hipMemsetAsync(edeg, 0, (size_t)N * 4, stream);

    // K1: layer-1 GEMM (raw) || edge histogram+rank || graph starts
    int g1 = 2 * (NG > NH ? NG : NH);
    k_gemm_hist<<<g1, 256, 0, stream>>>(x, w0, Hs, N, K0, NG,
                                        edst, batch, edeg, rank, starts, E, N, NH);

    // CSR offsets (scan fused with dinv)
    k_scan1<<<nb, 256, 0, stream>>>(edeg, offs, bsum, dinv, N);
    k_scan2<<<1, 256, 0, stream>>>(bsum, boff, nb);
    k_scan3<<<nb, 256, 0, stream>>>(offs, boff, N, E);

    // CSR fill (no atomics)
    k_fill<<<(E / 4 + 255) / 256 + 1, 256, 0, stream>>>(esrc, edst, rank, offs, csr, E);

    // layer 1 aggregate (deferred dinv on gathered rows)
    k_agg<true, false><<<agg_grid, 256, 0, stream>>>(Hs, csr, offs, dinv, b0, h1, N, nullptr, nullptr);
    // layer 2
    k_gemm<<<NG, 256, 0, stream>>>(h1, w1, dinv, Hs, N, HID);
    k_agg<false, false><<<agg_grid, 256, 0, stream>>>(Hs, csr, offs, dinv, b1, h2, N, nullptr, nullptr);
    // layer 3 (+ fused layer-4 prescaled GEMV -> ts)
    k_gemm<<<NG, 256, 0, stream>>>(h2, w2, dinv, Hs, N, HID);
    k_agg<false, true><<<agg_grid, 256, 0, stream>>>(Hs, csr, offs, dinv, b2, h3, N, w3, ts);
    // layer 4 aggregate + finish
    k_agg4<<<(N + 255) / 256, 256, 0, stream>>>(ts, csr, offs, dinv, b3, h4, N);

    // sort-pool top-30 per graph
    k_select<<<NGRAPH, 512, 0, stream>>>(h4, starts, sel);

    // tail
    k_tail<<<NGRAPH, 1024, 0, stream>>>(h1, h2, h3, h4, sel,
                                        c1w, c1b, c2w, c2b,
                                        l1w, l1b, l2w, l2b,
                                        (float*)d_out);
}